// Round 10
// baseline (722.895 us; speedup 1.0000x reference)
//
#include <hip/hip_runtime.h>
#include <hip/hip_bf16.h>
#include <cstdint>

typedef unsigned short u16;
typedef __attribute__((ext_vector_type(8))) short short8;
typedef __attribute__((ext_vector_type(4))) float floatx4;

#define PA_TOTAL 13696   // sum of per-level pixel counts, each padded to 128
#define CCH 256
#define KTOT 2304        // 9 taps * 256 ic

struct Tables {
  int H[5], W[5], P[5], base[5], tile0[5];
  int lb[5], bb[5], cb[5];   // d_out offsets: logits, bbox, centerness per level
};
struct FeatPtrs { const float* f[5]; };
struct ConvArgs {
  const u16* X[2];      // per-tower input activations
  const u16* Wt[2];     // per-tower weight matrices for this stage
  const u16* zbuf;
  u16* outB[2];         // per-tower conv output (bf16 NHWC)
  float* stats;         // [tower][ (b*5+lvl)*32+g ][2]  -> tower stride 640 floats
  float* dout;
  const float* biasCls; const float* biasCtr; const float* biasBox; const float* scales;
};

__device__ __forceinline__ u16 f2bf(float f) {
  union { float f; unsigned u; } v; v.f = f;
  unsigned r = v.u + 0x7fffu + ((v.u >> 16) & 1u);   // RNE
  return (u16)(r >> 16);
}
__device__ __forceinline__ float bf2f(u16 h) {
  union { unsigned u; float f; } v; v.u = ((unsigned)h) << 16;
  return v.f;
}

__device__ __forceinline__ void gl2lds16(const u16* g, u16* l) {
  __builtin_amdgcn_global_load_lds((const __attribute__((address_space(1))) unsigned int*)g,
                                   (__attribute__((address_space(3))) unsigned int*)l, 16, 0, 0);
}

// ---- weight reorder, coalesced: one block per row; read row [256 ic][9 tap] f32
// contiguously into LDS, write [9 tap][256 ic] bf16 contiguously.
// LDS read stride 9 floats -> gcd(9,32)=1 -> conflict-free.
__global__ void reorder_rows(const float* __restrict__ src, u16* __restrict__ out) {
  __shared__ float row[KTOT];
  const int r = blockIdx.x;
  const float* s = src + (size_t)r * KTOT;
  u16* o = out + (size_t)r * KTOT;
#pragma unroll
  for (int j = 0; j < 9; ++j) row[threadIdx.x + j * 256] = s[threadIdx.x + j * 256];
  __syncthreads();
#pragma unroll
  for (int j = 0; j < 9; ++j) {
    int k = threadIdx.x + j * 256;
    o[k] = f2bf(row[(k & 255) * 9 + (k >> 8)]);
  }
}

// cls_pred (20 rows) + ctr_pred (1 row) combined into 21-row weight matrix
__global__ void reorder_pred_cls(const float* __restrict__ cls_w, const float* __restrict__ ctr_w,
                                 u16* __restrict__ out) {
  __shared__ float row[KTOT];
  const int r = blockIdx.x;   // 0..20
  const float* s = (r < 20) ? (cls_w + (size_t)r * KTOT) : ctr_w;
  u16* o = out + (size_t)r * KTOT;
#pragma unroll
  for (int j = 0; j < 9; ++j) row[threadIdx.x + j * 256] = s[threadIdx.x + j * 256];
  __syncthreads();
#pragma unroll
  for (int j = 0; j < 9; ++j) {
    int k = threadIdx.x + j * 256;
    o[k] = f2bf(row[(k & 255) * 9 + (k >> 8)]);
  }
}

// ---- inputs NCHW f32 -> NHWC bf16, 32x32 LDS transpose (coalesced both sides)
// grid: (PA_TOTAL/32, 8, 2)  block 256
__global__ void convert_inputs(FeatPtrs fp, u16* __restrict__ out, Tables tb) {
  __shared__ float tile[32][33];
  const int pt = blockIdx.x, c32 = blockIdx.y, b = blockIdx.z;
  const int p0 = pt * 32;
  int lvl = 0;
#pragma unroll
  for (int i = 1; i < 5; ++i) if (p0 >= tb.base[i]) lvl = i;
  const int P = tb.P[lvl];
  const int pl0 = p0 - tb.base[lvl];
  const int r = threadIdx.x >> 5, col = threadIdx.x & 31;
  const float* src = fp.f[lvl] + ((size_t)b * CCH + c32 * 32) * P;
#pragma unroll
  for (int i = 0; i < 4; ++i) {
    int crow = r + i * 8;
    int pl = pl0 + col;
    tile[crow][col] = (pl < P) ? src[(size_t)crow * P + pl] : 0.f;
  }
  __syncthreads();
#pragma unroll
  for (int i = 0; i < 4; ++i) {
    int px = r + i * 8;
    out[((size_t)b * PA_TOTAL + p0 + px) * CCH + c32 * 32 + col] = f2bf(tile[col][px]);
  }
}

// ---- tower conv3x3: implicit-GEMM, bf16 MFMA 16x16x32, BK=64, single-buffered
// (R7/R9 plateau structure), XOR-swizzled LDS. 512-thread blocks: 2 pixel-tiles
// (2x128 px) share one W-tile (128 oc) -> barriers/W-staging amortized over 2x FLOP.
// Waves 0-3 compute tile A (t=2*slot), waves 4-7 tile B (t=2*slot+1; t==107 -> idle).
// XCD permute: L%8 selects (tower,mt,b) so W+X stay XCD-L2-resident.
// grid (54,2,4) = 432 = 54*8 exact.
__global__ __launch_bounds__(512) void conv_tower(ConvArgs a, Tables tb) {
  const int L = blockIdx.x + 54 * (blockIdx.y + 2 * blockIdx.z);
  const int xcd = L & 7, slot = L >> 3;
  const int tower = xcd >> 2, mt = (xcd >> 1) & 1, b = xcd & 1;

  const int tid = threadIdx.x;
  const int lane = tid & 63, wv = tid >> 6;
  const int g = wv >> 2, wg = wv & 3;          // group (tile half), wave-in-group
  const int wm = wg >> 1, wn = wg & 1;

  const int t = 2 * slot + g;
  const bool tvalid = (t < 107);
  const int te = tvalid ? t : 106;
  int lvl = 0;
#pragma unroll
  for (int i = 1; i < 5; ++i) if (te >= tb.tile0[i]) lvl = i;
  const int H = tb.H[lvl], W = tb.W[lvl], P = tb.P[lvl], base = tb.base[lvl];
  const int n0 = (te - tb.tile0[lvl]) * 128;

  __shared__ u16 ldsX[2 * 128 * 64];   // [group][px][64 ic] swizzled, 32KB
  __shared__ u16 ldsW[128 * 64];       // [oc][64 k] swizzled, 16KB (shared by both groups)

  const u16* X = a.X[tower];
  const u16* Wt = a.Wt[tower];
  const u16* zbuf = a.zbuf;

  // X staging: per group 1024 16B-chunks; thread handles 4 (t4) within its group.
  // chunk -> row=(t4*4+wg)*8+(lane>>3), col=lane&7; slot holds k-chunk q'=col^(row&7).
  const int qsw = (((lane & 7) ^ (lane >> 3))) * 8;   // u16 offset of fetched chunk
  int prow[4];
  unsigned mask9[4];
  int ldso[4];
#pragma unroll
  for (int t4 = 0; t4 < 4; ++t4) {
    int row = (t4 * 4 + wg) * 8 + (lane >> 3);
    prow[t4] = n0 + row;
    int rr = prow[t4] / W, cc = prow[t4] - rr * W;
    unsigned m = 0;
    if (tvalid) {
#pragma unroll
      for (int tap = 0; tap < 9; ++tap) {
        const int dh = tap / 3 - 1, dw = tap % 3 - 1;
        bool v = ((unsigned)(rr + dh) < (unsigned)H) & ((unsigned)(cc + dw) < (unsigned)W);
        m |= ((unsigned)v) << tap;
      }
    }
    mask9[t4] = m;
    ldso[t4] = g * 8192 + (t4 * 4 + wg) * 512;
  }
  // W staging: 1024 chunks over 512 threads -> 2 per thread (e=0,1).
  const u16* wsrc[2];
#pragma unroll
  for (int e = 0; e < 2; ++e) {
    int wrow = wv * 16 + e * 8 + (lane >> 3);
    wsrc[e] = Wt + (size_t)(mt * 128 + wrow) * KTOT + qsw;
  }
  const u16* Xbp = X + ((size_t)b * PA_TOTAL + base) * CCH;

  // fragment LDS offsets (u16), reader swizzle col = kq ^ (row&7)
  const int arow = lane & 15, rsw = lane & 7, kq0 = lane >> 4;
  int aoff[2][4], boff[2][4];
#pragma unroll
  for (int h = 0; h < 2; ++h) {
    int csw = (((h * 4 + kq0) ^ rsw)) * 8;
#pragma unroll
    for (int i = 0; i < 4; ++i) {
      aoff[h][i] = (wm * 64 + i * 16 + arow) * 64 + csw;
      boff[h][i] = g * 8192 + (wn * 64 + i * 16 + arow) * 64 + csw;
    }
  }

  floatx4 acc[4][4];
#pragma unroll
  for (int i = 0; i < 4; ++i)
#pragma unroll
    for (int j = 0; j < 4; ++j) acc[i][j] = (floatx4)0.f;

  // K-loop: icb outer, taps inner; 6 gl2lds16/thread/step (4 X-own + 2 W-shared).
#pragma unroll 1
  for (int icb = 0; icb < 4; ++icb) {
#pragma unroll
    for (int tap = 0; tap < 9; ++tap) {
      const int dh = tap / 3 - 1, dw = tap % 3 - 1;
      const int dpos = dh * W + dw;
      const int ko = tap * 256 + icb * 64;
      __syncthreads();
#pragma unroll
      for (int t4 = 0; t4 < 4; ++t4) {
        const u16* src = ((mask9[t4] >> tap) & 1)
            ? (Xbp + (size_t)(prow[t4] + dpos) * CCH + qsw + icb * 64) : zbuf;
        gl2lds16(src, ldsX + ldso[t4]);
      }
#pragma unroll
      for (int e = 0; e < 2; ++e)
        gl2lds16(wsrc[e] + ko, ldsW + wv * 1024 + e * 512);
      __syncthreads();
#pragma unroll
      for (int h = 0; h < 2; ++h) {
        short8 af[4], bv[4];
#pragma unroll
        for (int i = 0; i < 4; ++i) af[i] = *(const short8*)(ldsW + aoff[h][i]);
#pragma unroll
        for (int j = 0; j < 4; ++j) bv[j] = *(const short8*)(ldsX + boff[h][j]);
#pragma unroll
        for (int i = 0; i < 4; ++i)
#pragma unroll
          for (int j = 0; j < 4; ++j)
            acc[i][j] = __builtin_amdgcn_mfma_f32_16x16x32_bf16(af[i], bv[j], acc[i][j], 0, 0, 0);
      }
    }
  }

  // epilogue; D[m=(lane>>4)*4+r][n=lane&15]
  if (!tvalid) return;
  const int quad = lane >> 4, col = lane & 15;
  u16* convB = a.outB[tower];
  float s[4] = {0.f, 0.f, 0.f, 0.f}, ss[4] = {0.f, 0.f, 0.f, 0.f};
#pragma unroll
  for (int j = 0; j < 4; ++j) {
    int pl = n0 + wn * 64 + j * 16 + col;
    bool valid = pl < P;
    u16* dst = convB + ((size_t)b * PA_TOTAL + base + pl) * CCH + mt * 128 + wm * 64 + quad * 4;
#pragma unroll
    for (int i = 0; i < 4; ++i) {
      ushort4 hv;
#pragma unroll
      for (int r = 0; r < 4; ++r) {
        u16 hh = f2bf(acc[i][j][r]);
        ((u16*)&hv)[r] = hh;
        float vr = bf2f(hh);                    // accumulate ROUNDED value -> GN self-consistent
        if (valid) { s[i] += vr; ss[i] += vr * vr; }
      }
      if (valid) *(ushort4*)(dst + i * 16) = hv;
    }
  }
#pragma unroll
  for (int i = 0; i < 4; ++i) {
#pragma unroll
    for (int off = 16; off >= 1; off >>= 1) {
      s[i] += __shfl_down(s[i], off, 64);
      ss[i] += __shfl_down(ss[i], off, 64);
    }
  }
  if ((lane & 31) == 0) {
    int half = lane >> 5;
#pragma unroll
    for (int i = 0; i < 4; ++i) {
      float* st = a.stats + tower * 640 +
                  ((size_t)((b * 5 + lvl) * 32 + mt * 16 + wm * 8 + i * 2 + half)) * 2;
      atomicAdd(st, s[i]);
      atomicAdd(st + 1, ss[i]);
    }
  }
}

// ---- pred convs: 32x128 tile (21 / 4 real oc rows), 256 threads.
// tower 0: cls(20)+ctr(1) -> d_out NCHW; tower 1: box-exp(4).
// grid (108,2,2) = 432 = 54*8 (4 blocks guard out).
__global__ __launch_bounds__(256) void conv_pred(ConvArgs a, Tables tb) {
  const int L = blockIdx.x + 108 * (blockIdx.y + 2 * blockIdx.z);
  const int xcd = L & 7, slot = L >> 3;
  const int tower = xcd >> 2, b = (xcd >> 1) & 1;
  const int t = slot * 2 + (xcd & 1);
  if (t >= 107) return;
  int lvl = 0;
#pragma unroll
  for (int i = 1; i < 5; ++i) if (t >= tb.tile0[i]) lvl = i;
  const int H = tb.H[lvl], W = tb.W[lvl], P = tb.P[lvl], base = tb.base[lvl];
  const int n0 = (t - tb.tile0[lvl]) * 128;

  const int tid = threadIdx.x;
  const int lane = tid & 63, wv = tid >> 6;
  const int wm = wv >> 1, wn = wv & 1;

  __shared__ u16 ldsX[128 * 64];   // [px][64 ic] swizzled, 16KB
  __shared__ u16 ldsW[32 * 64];    // [oc][64 k] swizzled, 4KB

  const u16* X = a.X[tower];
  const u16* Wt = a.Wt[tower];
  const u16* zbuf = a.zbuf;

  const int qsw = (((lane & 7) ^ (lane >> 3))) * 8;
  int prow[4];
  unsigned mask9[4];
  int ldso[4];
#pragma unroll
  for (int t4 = 0; t4 < 4; ++t4) {
    int row = (t4 * 4 + wv) * 8 + (lane >> 3);
    prow[t4] = n0 + row;
    int rr = prow[t4] / W, cc = prow[t4] - rr * W;
    unsigned m = 0;
#pragma unroll
    for (int tap = 0; tap < 9; ++tap) {
      const int dh = tap / 3 - 1, dw = tap % 3 - 1;
      bool v = ((unsigned)(rr + dh) < (unsigned)H) & ((unsigned)(cc + dw) < (unsigned)W);
      m |= ((unsigned)v) << tap;
    }
    mask9[t4] = m;
    ldso[t4] = (t4 * 4 + wv) * 512;
  }
  const u16* wsrc = Wt + (size_t)(wv * 8 + (lane >> 3)) * KTOT + qsw;
  const u16* Xbp = X + ((size_t)b * PA_TOTAL + base) * CCH;

  const int arow = lane & 15, rsw = lane & 7, kq0 = lane >> 4;
  int aoff[2], boff[2][4];
#pragma unroll
  for (int h = 0; h < 2; ++h) {
    int csw = (((h * 4 + kq0) ^ rsw)) * 8;
    aoff[h] = (wm * 16 + arow) * 64 + csw;
#pragma unroll
    for (int i = 0; i < 4; ++i) boff[h][i] = (wn * 64 + i * 16 + arow) * 64 + csw;
  }

  floatx4 acc[4];
#pragma unroll
  for (int j = 0; j < 4; ++j) acc[j] = (floatx4)0.f;

#pragma unroll 1
  for (int icb = 0; icb < 4; ++icb) {
#pragma unroll
    for (int tap = 0; tap < 9; ++tap) {
      const int dh = tap / 3 - 1, dw = tap % 3 - 1;
      const int dpos = dh * W + dw;
      const int ko = tap * 256 + icb * 64;
      __syncthreads();
#pragma unroll
      for (int t4 = 0; t4 < 4; ++t4) {
        const u16* src = ((mask9[t4] >> tap) & 1)
            ? (Xbp + (size_t)(prow[t4] + dpos) * CCH + qsw + icb * 64) : zbuf;
        gl2lds16(src, ldsX + ldso[t4]);
      }
      gl2lds16(wsrc + ko, ldsW + wv * 512);
      __syncthreads();
#pragma unroll
      for (int h = 0; h < 2; ++h) {
        short8 af = *(const short8*)(ldsW + aoff[h]);
#pragma unroll
        for (int j = 0; j < 4; ++j) {
          short8 bv = *(const short8*)(ldsX + boff[h][j]);
          acc[j] = __builtin_amdgcn_mfma_f32_16x16x32_bf16(af, bv, acc[j], 0, 0, 0);
        }
      }
    }
  }

  const int quad = lane >> 4, col = lane & 15;
  float* dout = a.dout;
  if (tower == 0) {
#pragma unroll
    for (int j = 0; j < 4; ++j) {
      int pl = n0 + wn * 64 + j * 16 + col;
      if (pl >= P) continue;
      int ocb = wm * 16 + quad * 4;
#pragma unroll
      for (int r = 0; r < 4; ++r) {
        int oc = ocb + r;
        float v = acc[j][r];
        if (oc < 20)       dout[tb.lb[lvl] + ((size_t)b * 20 + oc) * P + pl] = v + a.biasCls[oc];
        else if (oc == 20) dout[tb.cb[lvl] + (size_t)b * P + pl] = v + a.biasCtr[0];
      }
    }
  } else {
    float sc = a.scales[lvl];
#pragma unroll
    for (int j = 0; j < 4; ++j) {
      int pl = n0 + wn * 64 + j * 16 + col;
      if (pl >= P) continue;
      int ocb = wm * 16 + quad * 4;
#pragma unroll
      for (int r = 0; r < 4; ++r) {
        int oc = ocb + r;
        if (oc < 4)
          dout[tb.bb[lvl] + ((size_t)b * 4 + oc) * P + pl] = expf((acc[j][r] + a.biasBox[oc]) * sc);
      }
    }
  }
}

// ---- GroupNorm pass 2: normalize + affine + ReLU, bf16 -> bf16, coalesced; both towers.
// grid (3424, 2): y = tower
__global__ void gn_norm(const u16* __restrict__ c0, const u16* __restrict__ c1,
                        const float* __restrict__ stats,
                        const float* __restrict__ g0, const float* __restrict__ b0,
                        const float* __restrict__ g1, const float* __restrict__ b1,
                        u16* __restrict__ a0, u16* __restrict__ a1, Tables tb) {
  const int tower = blockIdx.y;
  const u16* convB = tower ? c1 : c0;
  const float* gamma = tower ? g1 : g0;
  const float* beta = tower ? b1 : b0;
  u16* act = tower ? a1 : a0;
  int idx = blockIdx.x * 256 + threadIdx.x;
  int c8 = idx & 31;                 // == group index
  int rest = idx >> 5;
  int p = rest % PA_TOTAL;
  int b = rest / PA_TOTAL;
  int lvl = 0;
#pragma unroll
  for (int i = 1; i < 5; ++i) if (p >= tb.base[i]) lvl = i;
  if (p - tb.base[lvl] >= tb.P[lvl]) return;
  const float* st = stats + tower * 640 + ((size_t)((b * 5 + lvl) * 32 + c8)) * 2;
  float cnt = 8.f * (float)tb.P[lvl];
  float mean = st[0] / cnt;
  float var = st[1] / cnt - mean * mean;
  float inv = rsqrtf(var + 1e-5f);
  const short8 x = *(const short8*)(convB + ((size_t)b * PA_TOTAL + p) * CCH + c8 * 8);
  short8 o;
#pragma unroll
  for (int j = 0; j < 8; ++j) {
    float v = bf2f((u16)x[j]);
    float y = (v - mean) * inv * gamma[c8 * 8 + j] + beta[c8 * 8 + j];
    y = fmaxf(y, 0.f);
    o[j] = (short)f2bf(y);
  }
  *(short8*)(act + ((size_t)b * PA_TOTAL + p) * CCH + c8 * 8) = o;
}

extern "C" void kernel_launch(void* const* d_in, const int* in_sizes, int n_in,
                              void* d_out, int out_size, void* d_ws, size_t ws_size,
                              hipStream_t stream) {
  const float* feat[5];
  for (int i = 0; i < 5; ++i) feat[i] = (const float*)d_in[i];
  const float* cls_tw_w  = (const float*)d_in[5];
  const float* cls_tw_g  = (const float*)d_in[6];
  const float* cls_tw_b  = (const float*)d_in[7];
  const float* box_tw_w  = (const float*)d_in[8];
  const float* box_tw_g  = (const float*)d_in[9];
  const float* box_tw_b  = (const float*)d_in[10];
  const float* cls_pred_w = (const float*)d_in[11];
  const float* cls_pred_b = (const float*)d_in[12];
  const float* box_pred_w = (const float*)d_in[13];
  const float* box_pred_b = (const float*)d_in[14];
  const float* ctr_pred_w = (const float*)d_in[15];
  const float* ctr_pred_b = (const float*)d_in[16];
  const float* scales     = (const float*)d_in[17];
  float* out = (float*)d_out;

  char* ws = (char*)d_ws;
  u16*   zbuf   = (u16*)(ws);                        // 512 B zeros
  float* stats  = (float*)(ws + 512);                // 5120 B: [2 towers][320 groups][2]
  u16*   WrCls  = (u16*)(ws + 8192);                 // 1024 x 2304 bf16
  u16*   WrBox  = (u16*)(ws + 8192 + 4718592);
  u16*   WrPCls = (u16*)(ws + 8192 + 2 * 4718592);   // 128 x 2304 bf16 (21 used)
  u16*   WrPBox = (u16*)(ws + 8192 + 2 * 4718592 + 589824);
  u16*   bufIn   = (u16*)(ws + 10625024);
  u16*   bufAct0 = (u16*)(ws + 10625024 + 1 * (size_t)14024704);
  u16*   bufAct1 = (u16*)(ws + 10625024 + 2 * (size_t)14024704);
  u16*   bufCv0  = (u16*)(ws + 10625024 + 3 * (size_t)14024704);
  u16*   bufCv1  = (u16*)(ws + 10625024 + 4 * (size_t)14024704);

  Tables tb = { {100,50,25,13,7}, {100,50,25,13,7}, {10000,2500,625,169,49},
                {0,10112,12672,13312,13568}, {0,79,99,104,106},
                {0,400000,500000,525000,531760},
                {533720,613720,633720,638720,640072},
                {640464,660464,665464,666714,667052} };

  hipMemsetAsync(zbuf, 0, 512, stream);
  hipMemsetAsync(WrPCls, 0, 589824, stream);
  hipMemsetAsync(WrPBox, 0, 589824, stream);

  reorder_rows<<<1024, 256, 0, stream>>>(cls_tw_w, WrCls);
  reorder_rows<<<1024, 256, 0, stream>>>(box_tw_w, WrBox);
  reorder_pred_cls<<<21, 256, 0, stream>>>(cls_pred_w, ctr_pred_w, WrPCls);
  reorder_rows<<<4, 256, 0, stream>>>(box_pred_w, WrPBox);

  FeatPtrs fp = {{feat[0], feat[1], feat[2], feat[3], feat[4]}};
  convert_inputs<<<dim3(PA_TOTAL / 32, 8, 2), 256, 0, stream>>>(fp, bufIn, tb);

  ConvArgs a;
  a.zbuf = zbuf; a.stats = stats; a.dout = out;
  a.biasCls = cls_pred_b; a.biasCtr = ctr_pred_b; a.biasBox = box_pred_b; a.scales = scales;
  a.outB[0] = bufCv0; a.outB[1] = bufCv1;

  for (int s = 0; s < 4; ++s) {
    a.X[0] = (s == 0) ? bufIn : bufAct0;
    a.X[1] = (s == 0) ? bufIn : bufAct1;
    a.Wt[0] = WrCls + (size_t)s * 256 * KTOT;
    a.Wt[1] = WrBox + (size_t)s * 256 * KTOT;
    hipMemsetAsync(stats, 0, 5120, stream);
    conv_tower<<<dim3(54, 2, 4), 512, 0, stream>>>(a, tb);
    gn_norm<<<dim3(3424, 2), 256, 0, stream>>>(bufCv0, bufCv1, stats,
                                               cls_tw_g + s * 256, cls_tw_b + s * 256,
                                               box_tw_g + s * 256, box_tw_b + s * 256,
                                               bufAct0, bufAct1, tb);
  }
  a.X[0] = bufAct0; a.X[1] = bufAct1;
  a.Wt[0] = WrPCls; a.Wt[1] = WrPBox;
  conv_pred<<<dim3(108, 2, 2), 256, 0, stream>>>(a, tb);
}

// Round 11
// 641.983 us; speedup vs baseline: 1.1260x; 1.1260x over previous
//
#include <hip/hip_runtime.h>
#include <hip/hip_bf16.h>
#include <cstdint>

typedef unsigned short u16;
typedef __attribute__((ext_vector_type(8))) short short8;
typedef __attribute__((ext_vector_type(4))) float floatx4;
typedef __attribute__((ext_vector_type(4))) int intx4;

#define PA_TOTAL 13696   // sum of per-level pixel counts, each padded to 128
#define CCH 256
#define KTOT 2304        // 9 taps * 256 ic

struct Tables {
  int H[5], W[5], P[5], base[5], tile0[5];
  int lb[5], bb[5], cb[5];   // d_out offsets: logits, bbox, centerness per level
};
struct FeatPtrs { const float* f[5]; };
struct ConvArgs {
  const u16* X[2];      // per-tower input activations
  const u16* Wt[2];     // per-tower weight matrices for this stage
  const u16* zbuf;
  u16* outB[2];         // per-tower conv output (bf16 NHWC)
  float* stats;         // [tower][ (b*5+lvl)*32+g ][2]  -> tower stride 640 floats
  float* dout;
  const float* biasCls; const float* biasCtr; const float* biasBox; const float* scales;
};

__device__ __forceinline__ u16 f2bf(float f) {
  union { float f; unsigned u; } v; v.f = f;
  unsigned r = v.u + 0x7fffu + ((v.u >> 16) & 1u);   // RNE
  return (u16)(r >> 16);
}
__device__ __forceinline__ float bf2f(u16 h) {
  union { unsigned u; float f; } v; v.u = ((unsigned)h) << 16;
  return v.f;
}

// ---- weight reorder, coalesced: one block per row; read row [256 ic][9 tap] f32
// contiguously into LDS, write [9 tap][256 ic] bf16 contiguously.
// LDS read stride 9 floats -> gcd(9,32)=1 -> conflict-free.
__global__ void reorder_rows(const float* __restrict__ src, u16* __restrict__ out) {
  __shared__ float row[KTOT];
  const int r = blockIdx.x;
  const float* s = src + (size_t)r * KTOT;
  u16* o = out + (size_t)r * KTOT;
#pragma unroll
  for (int j = 0; j < 9; ++j) row[threadIdx.x + j * 256] = s[threadIdx.x + j * 256];
  __syncthreads();
#pragma unroll
  for (int j = 0; j < 9; ++j) {
    int k = threadIdx.x + j * 256;
    o[k] = f2bf(row[(k & 255) * 9 + (k >> 8)]);
  }
}

// cls_pred (20 rows) + ctr_pred (1 row) combined into 21-row weight matrix
__global__ void reorder_pred_cls(const float* __restrict__ cls_w, const float* __restrict__ ctr_w,
                                 u16* __restrict__ out) {
  __shared__ float row[KTOT];
  const int r = blockIdx.x;   // 0..20
  const float* s = (r < 20) ? (cls_w + (size_t)r * KTOT) : ctr_w;
  u16* o = out + (size_t)r * KTOT;
#pragma unroll
  for (int j = 0; j < 9; ++j) row[threadIdx.x + j * 256] = s[threadIdx.x + j * 256];
  __syncthreads();
#pragma unroll
  for (int j = 0; j < 9; ++j) {
    int k = threadIdx.x + j * 256;
    o[k] = f2bf(row[(k & 255) * 9 + (k >> 8)]);
  }
}

// ---- inputs NCHW f32 -> NHWC bf16, 32x32 LDS transpose (coalesced both sides)
// grid: (PA_TOTAL/32, 8, 2)  block 256
__global__ void convert_inputs(FeatPtrs fp, u16* __restrict__ out, Tables tb) {
  __shared__ float tile[32][33];
  const int pt = blockIdx.x, c32 = blockIdx.y, b = blockIdx.z;
  const int p0 = pt * 32;
  int lvl = 0;
#pragma unroll
  for (int i = 1; i < 5; ++i) if (p0 >= tb.base[i]) lvl = i;
  const int P = tb.P[lvl];
  const int pl0 = p0 - tb.base[lvl];
  const int r = threadIdx.x >> 5, col = threadIdx.x & 31;
  const float* src = fp.f[lvl] + ((size_t)b * CCH + c32 * 32) * P;
#pragma unroll
  for (int i = 0; i < 4; ++i) {
    int crow = r + i * 8;
    int pl = pl0 + col;
    tile[crow][col] = (pl < P) ? src[(size_t)crow * P + pl] : 0.f;
  }
  __syncthreads();
#pragma unroll
  for (int i = 0; i < 4; ++i) {
    int px = r + i * 8;
    out[((size_t)b * PA_TOTAL + p0 + px) * CCH + c32 * 32 + col] = f2bf(tile[col][px]);
  }
}

// ---- implicit-GEMM conv3x3 SAME, bf16 MFMA 16x16x32, BK=64, 128-px tiles
// (R9 plateau structure), XOR-swizzled LDS, towers merged in one dispatch.
// REGISTER-STAGED PREFETCH: global_load_dwordx4 -> VGPRs (thread-private, so
// __syncthreads needs NO vmcnt drain, unlike global_load_lds - the R8 failure);
// the vmcnt wait lands at the ds_write consuming the regs, one full compute
// phase after issue. Invalid halo lanes zero the register (no zbuf reads).
// XCD permute: L%8 selects (tower,mt,b) so W+X stay XCD-L2-resident.
// MODE 0: 128x128 tile, tower stage -> bf16 NHWC + fused GN stats. grid (107,2,4).
// MODE 1: 32x128 tile (21/4 real oc rows), pred convs -> d_out NCHW.
//         grid (108,2,2) = 432 = 54*8 (4 blocks guard out).
template <int MODE>
__global__ __launch_bounds__(256) void conv_mfma(ConvArgs a, Tables tb) {
  constexpr int NI = (MODE == 0) ? 4 : 1;     // A-frag rows per wave
  const int L = blockIdx.x + (MODE == 0 ? 107 : 108) * (blockIdx.y + 2 * blockIdx.z);
  const int xcd = L & 7, slot = L >> 3;
  int tower, mt, b, t;
  if (MODE == 0) {
    tower = xcd >> 2; mt = (xcd >> 1) & 1; b = xcd & 1; t = slot;
  } else {
    tower = xcd >> 2; mt = 0; b = (xcd >> 1) & 1; t = slot * 2 + (xcd & 1);
    if (t >= 107) return;
  }
  int lvl = 0;
#pragma unroll
  for (int i = 1; i < 5; ++i) if (t >= tb.tile0[i]) lvl = i;
  const int H = tb.H[lvl], W = tb.W[lvl], P = tb.P[lvl], base = tb.base[lvl];
  const int n0 = (t - tb.tile0[lvl]) * 128;

  const int tid = threadIdx.x;
  const int lane = tid & 63, wv = tid >> 6;
  const int wm = wv >> 1, wn = wv & 1;

  __shared__ u16 ldsX[128 * 64];                       // [px][64 ic] swizzled, 16KB
  __shared__ u16 ldsW[(MODE == 0 ? 128 : 32) * 64];    // [oc][64 k] swizzled

  const u16* X = a.X[tower];
  const u16* Wt = a.Wt[tower];

  // staging geometry: chunk ci = (t4*4+wv)*64 + lane -> row=ci>>3, col=lane&7;
  // slot (row,col) holds k-chunk q' = col ^ (row&7), a per-thread constant.
  const int qsw = (((lane & 7) ^ (lane >> 3))) * 8;   // u16 offset of fetched chunk
  int prow[4];
  unsigned mask9[4];
  int xdst[4];                       // per-lane LDS byte dests
#pragma unroll
  for (int t4 = 0; t4 < 4; ++t4) {
    int row = (t4 * 4 + wv) * 8 + (lane >> 3);
    prow[t4] = n0 + row;
    int rr = prow[t4] / W, cc = prow[t4] - rr * W;
    unsigned m = 0;
#pragma unroll
    for (int tap = 0; tap < 9; ++tap) {
      const int dh = tap / 3 - 1, dw = tap % 3 - 1;
      bool v = ((unsigned)(rr + dh) < (unsigned)H) & ((unsigned)(cc + dw) < (unsigned)W);
      m |= ((unsigned)v) << tap;
    }
    mask9[t4] = m;
    xdst[t4] = (t4 * 4 + wv) * 1024 + lane * 16;
  }
  const u16* wsrc[NI];
  int wdst[NI];
#pragma unroll
  for (int e = 0; e < NI; ++e) {
    int wrow = (MODE == 0) ? ((e * 4 + wv) * 8 + (lane >> 3)) : (wv * 8 + (lane >> 3));
    wsrc[e] = Wt + (size_t)(mt * 128 + wrow) * KTOT + qsw;
    wdst[e] = (MODE == 0) ? xdst[e] : (wv * 1024 + lane * 16);
  }
  const u16* Xbp = X + ((size_t)b * PA_TOTAL + base) * CCH;

  // fragment LDS offsets (u16), reader swizzle col = kq ^ (row&7)
  const int arow = lane & 15, rsw = lane & 7, kq0 = lane >> 4;
  int aoff[2][NI], boff[2][4];
#pragma unroll
  for (int h = 0; h < 2; ++h) {
    int csw = (((h * 4 + kq0) ^ rsw)) * 8;
#pragma unroll
    for (int i = 0; i < NI; ++i) {
      int rowb = (MODE == 0) ? (wm * 64 + i * 16) : (wm * 16);
      aoff[h][i] = (rowb + arow) * 64 + csw;
    }
#pragma unroll
    for (int i = 0; i < 4; ++i) boff[h][i] = (wn * 64 + i * 16 + arow) * 64 + csw;
  }

  floatx4 acc[NI][4];
#pragma unroll
  for (int i = 0; i < NI; ++i)
#pragma unroll
    for (int j = 0; j < 4; ++j) acc[i][j] = (floatx4)0.f;

  const intx4 zreg = {0, 0, 0, 0};
  intx4 xr[4], wr[NI];
  // prologue: issue loads for step (icb=0, tap=0); dpos = -W-1
  {
    const int dpos0 = -W - 1;
#pragma unroll
    for (int t4 = 0; t4 < 4; ++t4)
      xr[t4] = (mask9[t4] & 1)
          ? *(const intx4*)(Xbp + (size_t)(prow[t4] + dpos0) * CCH + qsw) : zreg;
#pragma unroll
    for (int e = 0; e < NI; ++e) wr[e] = *(const intx4*)(wsrc[e]);
  }

  // K-loop: icb outer, taps inner (unrolled). Per step: barrier (prev readers
  // done) -> ds_write staged regs (vmcnt wait here, loads are 1 step old) ->
  // issue next step's loads -> barrier (writes visible) -> MFMA.
#pragma unroll 1
  for (int icb = 0; icb < 4; ++icb) {
#pragma unroll
    for (int tap = 0; tap < 9; ++tap) {
      __syncthreads();
#pragma unroll
      for (int t4 = 0; t4 < 4; ++t4) *(intx4*)((char*)ldsX + xdst[t4]) = xr[t4];
#pragma unroll
      for (int e = 0; e < NI; ++e) *(intx4*)((char*)ldsW + wdst[e]) = wr[e];
      if (!(icb == 3 && tap == 8)) {
        const int ntap = (tap == 8) ? 0 : tap + 1;
        const int nicb = (tap == 8) ? icb + 1 : icb;
        const int ndh = ntap / 3;
        const int ndpos = (ndh - 1) * W + (ntap - 3 * ndh - 1);
        const int nko = ntap * 256 + nicb * 64;
#pragma unroll
        for (int t4 = 0; t4 < 4; ++t4)
          xr[t4] = ((mask9[t4] >> ntap) & 1)
              ? *(const intx4*)(Xbp + (size_t)(prow[t4] + ndpos) * CCH + qsw + nicb * 64) : zreg;
#pragma unroll
        for (int e = 0; e < NI; ++e) wr[e] = *(const intx4*)(wsrc[e] + nko);
      }
      __syncthreads();
#pragma unroll
      for (int h = 0; h < 2; ++h) {
        short8 af[NI], bv[4];
#pragma unroll
        for (int i = 0; i < NI; ++i) af[i] = *(const short8*)(ldsW + aoff[h][i]);
#pragma unroll
        for (int j = 0; j < 4; ++j) bv[j] = *(const short8*)(ldsX + boff[h][j]);
#pragma unroll
        for (int i = 0; i < NI; ++i)
#pragma unroll
          for (int j = 0; j < 4; ++j)
            acc[i][j] = __builtin_amdgcn_mfma_f32_16x16x32_bf16(af[i], bv[j], acc[i][j], 0, 0, 0);
      }
    }
  }

  // epilogue; D[m=(lane>>4)*4+r][n=lane&15]
  const int quad = lane >> 4, col = lane & 15;
  if (MODE == 0) {
    u16* convB = a.outB[tower];
    float s[4] = {0.f, 0.f, 0.f, 0.f}, ss[4] = {0.f, 0.f, 0.f, 0.f};
#pragma unroll
    for (int j = 0; j < 4; ++j) {
      int pl = n0 + wn * 64 + j * 16 + col;
      bool valid = pl < P;
      u16* dst = convB + ((size_t)b * PA_TOTAL + base + pl) * CCH + mt * 128 + wm * 64 + quad * 4;
#pragma unroll
      for (int i = 0; i < 4; ++i) {
        ushort4 hv;
#pragma unroll
        for (int r = 0; r < 4; ++r) {
          u16 hh = f2bf(acc[i][j][r]);
          ((u16*)&hv)[r] = hh;
          float vr = bf2f(hh);                    // accumulate ROUNDED value -> GN self-consistent
          if (valid) { s[i] += vr; ss[i] += vr * vr; }
        }
        if (valid) *(ushort4*)(dst + i * 16) = hv;
      }
    }
#pragma unroll
    for (int i = 0; i < 4; ++i) {
#pragma unroll
      for (int off = 16; off >= 1; off >>= 1) {
        s[i] += __shfl_down(s[i], off, 64);
        ss[i] += __shfl_down(ss[i], off, 64);
      }
    }
    if ((lane & 31) == 0) {
      int half = lane >> 5;
#pragma unroll
      for (int i = 0; i < 4; ++i) {
        float* st = a.stats + tower * 640 +
                    ((size_t)((b * 5 + lvl) * 32 + mt * 16 + wm * 8 + i * 2 + half)) * 2;
        atomicAdd(st, s[i]);
        atomicAdd(st + 1, ss[i]);
      }
    }
  } else {
    float* dout = a.dout;
    if (tower == 0) {
#pragma unroll
      for (int j = 0; j < 4; ++j) {
        int pl = n0 + wn * 64 + j * 16 + col;
        if (pl >= P) continue;
        int ocb = wm * 16 + quad * 4;
#pragma unroll
        for (int r = 0; r < 4; ++r) {
          int oc = ocb + r;
          float v = acc[0][j][r];
          if (oc < 20)       dout[tb.lb[lvl] + ((size_t)b * 20 + oc) * P + pl] = v + a.biasCls[oc];
          else if (oc == 20) dout[tb.cb[lvl] + (size_t)b * P + pl] = v + a.biasCtr[0];
        }
      }
    } else {
      float sc = a.scales[lvl];
#pragma unroll
      for (int j = 0; j < 4; ++j) {
        int pl = n0 + wn * 64 + j * 16 + col;
        if (pl >= P) continue;
        int ocb = wm * 16 + quad * 4;
#pragma unroll
        for (int r = 0; r < 4; ++r) {
          int oc = ocb + r;
          if (oc < 4)
            dout[tb.bb[lvl] + ((size_t)b * 4 + oc) * P + pl] = expf((acc[0][j][r] + a.biasBox[oc]) * sc);
        }
      }
    }
  }
}

// ---- GroupNorm pass 2: normalize + affine + ReLU, bf16 -> bf16, coalesced; both towers.
// grid (3424, 2): y = tower
__global__ void gn_norm(const u16* __restrict__ c0, const u16* __restrict__ c1,
                        const float* __restrict__ stats,
                        const float* __restrict__ g0, const float* __restrict__ b0,
                        const float* __restrict__ g1, const float* __restrict__ b1,
                        u16* __restrict__ a0, u16* __restrict__ a1, Tables tb) {
  const int tower = blockIdx.y;
  const u16* convB = tower ? c1 : c0;
  const float* gamma = tower ? g1 : g0;
  const float* beta = tower ? b1 : b0;
  u16* act = tower ? a1 : a0;
  int idx = blockIdx.x * 256 + threadIdx.x;
  int c8 = idx & 31;                 // == group index
  int rest = idx >> 5;
  int p = rest % PA_TOTAL;
  int b = rest / PA_TOTAL;
  int lvl = 0;
#pragma unroll
  for (int i = 1; i < 5; ++i) if (p >= tb.base[i]) lvl = i;
  if (p - tb.base[lvl] >= tb.P[lvl]) return;
  const float* st = stats + tower * 640 + ((size_t)((b * 5 + lvl) * 32 + c8)) * 2;
  float cnt = 8.f * (float)tb.P[lvl];
  float mean = st[0] / cnt;
  float var = st[1] / cnt - mean * mean;
  float inv = rsqrtf(var + 1e-5f);
  const short8 x = *(const short8*)(convB + ((size_t)b * PA_TOTAL + p) * CCH + c8 * 8);
  short8 o;
#pragma unroll
  for (int j = 0; j < 8; ++j) {
    float v = bf2f((u16)x[j]);
    float y = (v - mean) * inv * gamma[c8 * 8 + j] + beta[c8 * 8 + j];
    y = fmaxf(y, 0.f);
    o[j] = (short)f2bf(y);
  }
  *(short8*)(act + ((size_t)b * PA_TOTAL + p) * CCH + c8 * 8) = o;
}

extern "C" void kernel_launch(void* const* d_in, const int* in_sizes, int n_in,
                              void* d_out, int out_size, void* d_ws, size_t ws_size,
                              hipStream_t stream) {
  const float* feat[5];
  for (int i = 0; i < 5; ++i) feat[i] = (const float*)d_in[i];
  const float* cls_tw_w  = (const float*)d_in[5];
  const float* cls_tw_g  = (const float*)d_in[6];
  const float* cls_tw_b  = (const float*)d_in[7];
  const float* box_tw_w  = (const float*)d_in[8];
  const float* box_tw_g  = (const float*)d_in[9];
  const float* box_tw_b  = (const float*)d_in[10];
  const float* cls_pred_w = (const float*)d_in[11];
  const float* cls_pred_b = (const float*)d_in[12];
  const float* box_pred_w = (const float*)d_in[13];
  const float* box_pred_b = (const float*)d_in[14];
  const float* ctr_pred_w = (const float*)d_in[15];
  const float* ctr_pred_b = (const float*)d_in[16];
  const float* scales     = (const float*)d_in[17];
  float* out = (float*)d_out;

  char* ws = (char*)d_ws;
  u16*   zbuf   = (u16*)(ws);                        // 512 B zeros
  float* stats  = (float*)(ws + 512);                // 5120 B: [2 towers][320 groups][2]
  u16*   WrCls  = (u16*)(ws + 8192);                 // 1024 x 2304 bf16
  u16*   WrBox  = (u16*)(ws + 8192 + 4718592);
  u16*   WrPCls = (u16*)(ws + 8192 + 2 * 4718592);   // 128 x 2304 bf16 (21 used)
  u16*   WrPBox = (u16*)(ws + 8192 + 2 * 4718592 + 589824);
  u16*   bufIn   = (u16*)(ws + 10625024);
  u16*   bufAct0 = (u16*)(ws + 10625024 + 1 * (size_t)14024704);
  u16*   bufAct1 = (u16*)(ws + 10625024 + 2 * (size_t)14024704);
  u16*   bufCv0  = (u16*)(ws + 10625024 + 3 * (size_t)14024704);
  u16*   bufCv1  = (u16*)(ws + 10625024 + 4 * (size_t)14024704);

  Tables tb = { {100,50,25,13,7}, {100,50,25,13,7}, {10000,2500,625,169,49},
                {0,10112,12672,13312,13568}, {0,79,99,104,106},
                {0,400000,500000,525000,531760},
                {533720,613720,633720,638720,640072},
                {640464,660464,665464,666714,667052} };

  hipMemsetAsync(zbuf, 0, 512, stream);
  hipMemsetAsync(WrPCls, 0, 589824, stream);
  hipMemsetAsync(WrPBox, 0, 589824, stream);

  reorder_rows<<<1024, 256, 0, stream>>>(cls_tw_w, WrCls);
  reorder_rows<<<1024, 256, 0, stream>>>(box_tw_w, WrBox);
  reorder_pred_cls<<<21, 256, 0, stream>>>(cls_pred_w, ctr_pred_w, WrPCls);
  reorder_rows<<<4, 256, 0, stream>>>(box_pred_w, WrPBox);

  FeatPtrs fp = {{feat[0], feat[1], feat[2], feat[3], feat[4]}};
  convert_inputs<<<dim3(PA_TOTAL / 32, 8, 2), 256, 0, stream>>>(fp, bufIn, tb);

  ConvArgs a;
  a.zbuf = zbuf; a.stats = stats; a.dout = out;
  a.biasCls = cls_pred_b; a.biasCtr = ctr_pred_b; a.biasBox = box_pred_b; a.scales = scales;
  a.outB[0] = bufCv0; a.outB[1] = bufCv1;

  for (int s = 0; s < 4; ++s) {
    a.X[0] = (s == 0) ? bufIn : bufAct0;
    a.X[1] = (s == 0) ? bufIn : bufAct1;
    a.Wt[0] = WrCls + (size_t)s * 256 * KTOT;
    a.Wt[1] = WrBox + (size_t)s * 256 * KTOT;
    hipMemsetAsync(stats, 0, 5120, stream);
    conv_mfma<0><<<dim3(107, 2, 4), 256, 0, stream>>>(a, tb);
    gn_norm<<<dim3(3424, 2), 256, 0, stream>>>(bufCv0, bufCv1, stats,
                                               cls_tw_g + s * 256, cls_tw_b + s * 256,
                                               box_tw_g + s * 256, box_tw_b + s * 256,
                                               bufAct0, bufAct1, tb);
  }
  a.X[0] = bufAct0; a.X[1] = bufAct1;
  a.Wt[0] = WrPCls; a.Wt[1] = WrPBox;
  conv_mfma<1><<<dim3(108, 2, 2), 256, 0, stream>>>(a, tb);
}